// Round 2
// baseline (36.019 us; speedup 1.0000x reference)
//
#include <hip/hip_runtime.h>

// 3D neighborhood attention, 40^3 grid, NH=8, HD=6, KS=3 (27 neighbors).
// out[c=h*3+o][vox] = sum_k p_k*off_k[o], p = softmax(q.k*scale + rpb).
// OOB neighbors: zero-padded k -> score = rpb only (still in softmax).
// Thread = (voxel, head-pair). No max-subtract (scores bounded << 88).
// exp(s) computed as exp2(s*log2e) with log2e folded into q-scale and rpb.

#define GS    40
#define NVOX  (GS*GS*GS)   // 64000

__global__ __launch_bounds__(256) void natt_kernel(
    const float* __restrict__ q, const float* __restrict__ kk,
    const float* __restrict__ rpb, float* __restrict__ out)
{
    // srpb[hp][n][2]: rpb (pre-scaled by log2e) for the two heads of pair hp
    __shared__ float srpb[4 * 27 * 2];
    int t = threadIdx.x;
    if (t < 216) {
        int h = t / 27, n = t % 27;
        srpb[((h >> 1) * 27 + n) * 2 + (h & 1)] = rpb[t] * 1.4426950408889634f;
    }
    __syncthreads();

    int tid = blockIdx.x * 256 + t;
    int hp  = tid & 3;        // head pair (heads 2hp, 2hp+1)
    int vox = tid >> 2;       // linear voxel, z fastest
    int z  = vox % GS;
    int xy = vox / GS;
    int y  = xy % GS;
    int x  = xy / GS;

    // q slice for this head pair, pre-scaled by 6^-0.5 * log2(e)
    const float QS = 0.4082482904638631f * 1.4426950408889634f;
    const float4* qp = (const float4*)(q + (size_t)vox * 48 + hp * 12);
    float4 qa = qp[0], qb = qp[1], qc = qp[2];
    float q0 = qa.x*QS, q1 = qa.y*QS, q2  = qa.z*QS, q3  = qa.w*QS;
    float q4 = qb.x*QS, q5 = qb.y*QS, q6  = qb.z*QS, q7  = qb.w*QS;
    float q8 = qc.x*QS, q9 = qc.y*QS, q10 = qc.z*QS, q11 = qc.w*QS;

    // per-axis clamped coords + validity masks
    int   xc[3], yc[3], zc[3];
    float mxf[3], myf[3], mzf[3];
    #pragma unroll
    for (int a = 0; a < 3; ++a) {
        int xx = x + a - 1, yy = y + a - 1, zz = z + a - 1;
        mxf[a] = ((unsigned)xx < GS) ? 1.0f : 0.0f;
        myf[a] = ((unsigned)yy < GS) ? 1.0f : 0.0f;
        mzf[a] = ((unsigned)zz < GS) ? 1.0f : 0.0f;
        xc[a] = min(max(xx, 0), GS - 1);
        yc[a] = min(max(yy, 0), GS - 1);
        zc[a] = min(max(zz, 0), GS - 1);
    }
    // 9 row bases (element index into kk) and combined x*y masks
    int   rb[9];
    float mxy[9];
    #pragma unroll
    for (int i = 0; i < 3; ++i)
    #pragma unroll
    for (int j = 0; j < 3; ++j) {
        rb[i*3+j]  = (xc[i] * 1600 + yc[j] * 40) * 48 + hp * 12;
        mxy[i*3+j] = mxf[i] * myf[j];
    }
    int zo[3] = { zc[0] * 48, zc[1] * 48, zc[2] * 48 };

    float d0 = 0, d1 = 0;
    float ox0 = 0, ox1 = 0, oy0 = 0, oy1 = 0, oz0 = 0, oz1 = 0;

    #pragma unroll
    for (int i = 0; i < 3; ++i)
    #pragma unroll
    for (int j = 0; j < 3; ++j) {
        int   rbij = rb[i*3+j];
        float mij  = mxy[i*3+j];
        #pragma unroll
        for (int l = 0; l < 3; ++l) {
            const float4* kp = (const float4*)(kk + rbij + zo[l]);
            float4 ka = kp[0], kb = kp[1], kc = kp[2];
            float m = mij * mzf[l];
            float dot0 = q0*ka.x + q1*ka.y + q2*ka.z + q3*ka.w + q4*kb.x + q5*kb.y;
            float dot1 = q6*kb.z + q7*kb.w + q8*kc.x + q9*kc.y + q10*kc.z + q11*kc.w;
            int n = i*9 + j*3 + l;
            float rp0 = srpb[(hp*27 + n)*2 + 0];
            float rp1 = srpb[(hp*27 + n)*2 + 1];
            float e0 = __builtin_amdgcn_exp2f(m * dot0 + rp0);
            float e1 = __builtin_amdgcn_exp2f(m * dot1 + rp1);
            d0 += e0; d1 += e1;
            if (i == 0)      { ox0 -= e0; ox1 -= e1; }
            else if (i == 2) { ox0 += e0; ox1 += e1; }
            if (j == 0)      { oy0 -= e0; oy1 -= e1; }
            else if (j == 2) { oy0 += e0; oy1 += e1; }
            if (l == 0)      { oz0 -= e0; oz1 -= e1; }
            else if (l == 2) { oz0 += e0; oz1 += e1; }
        }
    }

    float inv0 = __builtin_amdgcn_rcpf(d0);
    float inv1 = __builtin_amdgcn_rcpf(d1);
    float* op = out + (size_t)(hp * 6) * NVOX + vox;
    op[0*NVOX] = ox0 * inv0;
    op[1*NVOX] = oy0 * inv0;
    op[2*NVOX] = oz0 * inv0;
    op[3*NVOX] = ox1 * inv1;
    op[4*NVOX] = oy1 * inv1;
    op[5*NVOX] = oz1 * inv1;
}

extern "C" void kernel_launch(void* const* d_in, const int* in_sizes, int n_in,
                              void* d_out, int out_size, void* d_ws, size_t ws_size,
                              hipStream_t stream) {
    const float* q   = (const float*)d_in[0];
    const float* k   = (const float*)d_in[1];
    const float* rpb = (const float*)d_in[2];
    float* out = (float*)d_out;

    int total = NVOX * 4;                 // one thread per (voxel, head-pair)
    int block = 256;
    int grid  = total / block;            // 1000
    natt_kernel<<<grid, block, 0, stream>>>(q, k, rpb, out);
}

// Round 3
// 25.314 us; speedup vs baseline: 1.4229x; 1.4229x over previous
//
#include <hip/hip_runtime.h>

// 3D neighborhood attention, 40^3, NH=8, HD=6, KS=3 (27 neighbors).
// Block = 4x4x4 voxel tile x 4 head-pairs (256 thr). k-halo (6x6x6 voxels)
// staged into LDS with dense float4 loads; OOB halo zero-filled so the
// zero-pad softmax semantics (score = rpb for OOB) need no masks.
// exp(s) = exp2(s*log2e): log2e folded into q-scale and rpb.

#define GS    40
#define NVOX  (GS*GS*GS)
#define HVOX  216          // 6*6*6 halo voxels
#define HPS   650          // per-head-pair LDS stride in float4 (216*3 + 2 pad)

__global__ __launch_bounds__(256) void natt_kernel(
    const float* __restrict__ q, const float* __restrict__ kk,
    const float* __restrict__ rpb, float* __restrict__ out)
{
    __shared__ float4 k4[4 * HPS];      // [hp][216 vox][3 f4] (+2 f4 pad/hp)
    __shared__ float  srpb[4 * 27 * 2]; // [hp][27][2 heads], pre-scaled log2e

    int t = threadIdx.x;
    int b = blockIdx.x;
    int bz = b % 10, by = (b / 10) % 10, bx = b / 100;
    int x0 = bx * 4, y0 = by * 4, z0 = bz * 4;

    if (t < 216) {
        int h = t / 27, n = t % 27;
        srpb[((h >> 1) * 27 + n) * 2 + (h & 1)] = rpb[t] * 1.4426950408889634f;
    }

    // ---- stage k halo: 36 (x,y) rows x 6 z x 12 f4 = 2592 f4, dense ----
    const float4* kk4 = (const float4*)kk;
    #pragma unroll
    for (int w = 0; w < 11; ++w) {
        int idx = t + w * 256;
        if (idx < 2592) {
            int row = idx / 72;          // 0..35  (xi*6+yi)
            int off = idx - row * 72;
            int v   = off / 12;          // z within row, 0..5
            int g   = off - v * 12;      // f4 within voxel, 0..11
            int xi = row / 6, yi = row - xi * 6;
            int gx = x0 + xi - 1, gy = y0 + yi - 1, gz = z0 + v - 1;
            float4 val = make_float4(0.f, 0.f, 0.f, 0.f);
            if (((unsigned)gx < GS) & ((unsigned)gy < GS) & ((unsigned)gz < GS))
                val = kk4[(gx * 1600 + gy * 40 + gz) * 12 + g];
            int hp_c = g / 3, cc = g - hp_c * 3;
            k4[hp_c * HPS + (row * 6 + v) * 3 + cc] = val;
        }
    }

    // ---- q load (independent of LDS) ----
    int hp = t & 3;
    int v  = t >> 2;          // 0..63
    int vz = v & 3, vy = (v >> 2) & 3, vx = v >> 4;
    int gvox = (x0 + vx) * 1600 + (y0 + vy) * 40 + (z0 + vz);

    const float QS = 0.4082482904638631f * 1.4426950408889634f;
    const float4* qp = (const float4*)q + (size_t)gvox * 12 + hp * 3;
    float4 qa = qp[0], qb = qp[1], qc = qp[2];
    float q0 = qa.x*QS, q1 = qa.y*QS, q2  = qa.z*QS, q3  = qa.w*QS;
    float q4 = qb.x*QS, q5 = qb.y*QS, q6  = qb.z*QS, q7  = qb.w*QS;
    float q8 = qc.x*QS, q9 = qc.y*QS, q10 = qc.z*QS, q11 = qc.w*QS;

    __syncthreads();

    float d0 = 0, d1 = 0;
    float ox0 = 0, ox1 = 0, oy0 = 0, oy1 = 0, oz0 = 0, oz1 = 0;

    const float4* kbase = k4 + hp * HPS;
    const float*  rpbase = srpb + hp * 54;

    #pragma unroll
    for (int i = 0; i < 3; ++i)
    #pragma unroll
    for (int j = 0; j < 3; ++j) {
        int hv = ((vx + i) * 36 + (vy + j) * 6 + vz) * 3;   // f4 index of l=0
        #pragma unroll
        for (int l = 0; l < 3; ++l) {
            float4 ka = kbase[hv + l * 3 + 0];
            float4 kb = kbase[hv + l * 3 + 1];
            float4 kc = kbase[hv + l * 3 + 2];
            int n = i * 9 + j * 3 + l;
            float dot0 = q0*ka.x + q1*ka.y + q2*ka.z + q3*ka.w + q4*kb.x + q5*kb.y;
            float dot1 = q6*kb.z + q7*kb.w + q8*kc.x + q9*kc.y + q10*kc.z + q11*kc.w;
            float e0 = __builtin_amdgcn_exp2f(dot0 + rpbase[n * 2 + 0]);
            float e1 = __builtin_amdgcn_exp2f(dot1 + rpbase[n * 2 + 1]);
            d0 += e0; d1 += e1;
            if (i == 0)      { ox0 -= e0; ox1 -= e1; }
            else if (i == 2) { ox0 += e0; ox1 += e1; }
            if (j == 0)      { oy0 -= e0; oy1 -= e1; }
            else if (j == 2) { oy0 += e0; oy1 += e1; }
            if (l == 0)      { oz0 -= e0; oz1 -= e1; }
            else if (l == 2) { oz0 += e0; oz1 += e1; }
        }
    }

    float inv0 = __builtin_amdgcn_rcpf(d0);
    float inv1 = __builtin_amdgcn_rcpf(d1);
    float* op = out + (size_t)(hp * 6) * NVOX + gvox;
    op[0*NVOX] = ox0 * inv0;
    op[1*NVOX] = oy0 * inv0;
    op[2*NVOX] = oz0 * inv0;
    op[3*NVOX] = ox1 * inv1;
    op[4*NVOX] = oy1 * inv1;
    op[5*NVOX] = oz1 * inv1;
}

extern "C" void kernel_launch(void* const* d_in, const int* in_sizes, int n_in,
                              void* d_out, int out_size, void* d_ws, size_t ws_size,
                              hipStream_t stream) {
    const float* q   = (const float*)d_in[0];
    const float* k   = (const float*)d_in[1];
    const float* rpb = (const float*)d_in[2];
    float* out = (float*)d_out;

    natt_kernel<<<1000, 256, 0, stream>>>(q, k, rpb, out);
}

// Round 5
// 24.778 us; speedup vs baseline: 1.4536x; 1.0216x over previous
//
#include <hip/hip_runtime.h>

// 3D neighborhood attention, 40^3, NH=8, HD=6, KS=3 (27 neighbors).
// Block = 4x4x4 voxel tile x 4 head-pairs (256 thr). 6x6x6 k-halo staged in
// LDS as packed bf16 (exact zero-fill for OOB -> score = rpb semantics).
// LDS layout [hp][216 vox][6 dw], hp stride 1304 dw -> 4 words/bank exact.
// 7 blocks/CU resident; XCD-chunked block swizzle for halo L2 sharing.
// exp(s)=exp2(s*log2e): log2e folded into q-scale and rpb.

#define GS    40
#define NVOX  (GS*GS*GS)
#define HPW   1304          // per-head-pair LDS stride in dwords (216*6 + 8)

__device__ __forceinline__ unsigned int bf16_rne(float f) {
    unsigned int b = __builtin_bit_cast(unsigned int, f);
    return (b + 0x7fffu + ((b >> 16) & 1u)) >> 16;   // exact RNE for normals
}

__global__ __launch_bounds__(256) void natt_kernel(
    const float* __restrict__ q, const float* __restrict__ kk,
    const float* __restrict__ rpb, float* __restrict__ out)
{
    __shared__ unsigned int sk[4 * HPW];   // 20.9 KB
    __shared__ float srpb[4 * 27 * 2];

    int t = threadIdx.x;
    int b = blockIdx.x;
    int w = (b & 7) * 125 + (b >> 3);      // XCD chunking (bijective: 1000=8*125)
    int bz = w % 10, by = (w / 10) % 10, bx = w / 100;
    int x0 = bx * 4, y0 = by * 4, z0 = bz * 4;

    if (t < 216) {
        int h = t / 27, n = t % 27;
        srpb[((h >> 1) * 27 + n) * 2 + (h & 1)] = rpb[t] * 1.4426950408889634f;
    }

    // ---- stage k halo as bf16: 36 rows x 6 z x 12 f4 = 2592 dense f4 ----
    const float4* kk4 = (const float4*)kk;
    #pragma unroll
    for (int it = 0; it < 11; ++it) {
        int idx = t + it * 256;
        if (idx < 2592) {
            int row = idx / 72;            // xi*6+yi
            int off = idx - row * 72;
            int v   = off / 12;            // z in halo row
            int g   = off - v * 12;        // f4 within voxel
            int xi = row / 6, yi = row - xi * 6;
            int gx = x0 + xi - 1, gy = y0 + yi - 1, gz = z0 + v - 1;
            float4 val = make_float4(0.f, 0.f, 0.f, 0.f);
            if (((unsigned)gx < GS) & ((unsigned)gy < GS) & ((unsigned)gz < GS))
                val = kk4[(gx * 1600 + gy * 40 + gz) * 12 + g];
            int hp_c = g / 3, cc = g - hp_c * 3;
            uint2 u;
            u.x = bf16_rne(val.x) | (bf16_rne(val.y) << 16);
            u.y = bf16_rne(val.z) | (bf16_rne(val.w) << 16);
            *(uint2*)(sk + hp_c * HPW + (row * 6 + v) * 6 + cc * 2) = u;
        }
    }

    // ---- q load (f32, pre-scaled), overlaps staging ----
    int hp = t & 3;
    int v  = t >> 2;
    int vz = v & 3, vy = (v >> 2) & 3, vx = v >> 4;
    int gvox = (x0 + vx) * 1600 + (y0 + vy) * 40 + (z0 + vz);

    const float QS = 0.4082482904638631f * 1.4426950408889634f;
    const float4* qp = (const float4*)q + (size_t)gvox * 12 + hp * 3;
    float4 qa = qp[0], qb = qp[1], qc = qp[2];
    float q0 = qa.x*QS, q1 = qa.y*QS, q2  = qa.z*QS, q3  = qa.w*QS;
    float q4 = qb.x*QS, q5 = qb.y*QS, q6  = qb.z*QS, q7  = qb.w*QS;
    float q8 = qc.x*QS, q9 = qc.y*QS, q10 = qc.z*QS, q11 = qc.w*QS;

    __syncthreads();

    float d0 = 0, d1 = 0;
    float ox0 = 0, ox1 = 0, oy0 = 0, oy1 = 0, oz0 = 0, oz1 = 0;

    const unsigned int* kb = sk + hp * HPW;
    const float* rpbase = srpb + hp * 54;

    #pragma unroll
    for (int i = 0; i < 3; ++i)
    #pragma unroll
    for (int j = 0; j < 3; ++j) {
        int hv0 = (vx + i) * 36 + (vy + j) * 6 + vz;
        #pragma unroll
        for (int l = 0; l < 3; ++l) {
            const uint2* p = (const uint2*)(kb + (hv0 + l) * 6);
            uint2 uA = p[0], uB = p[1], uC = p[2];
            float k0  = __builtin_bit_cast(float, uA.x << 16);
            float k1  = __builtin_bit_cast(float, uA.x & 0xffff0000u);
            float k2  = __builtin_bit_cast(float, uA.y << 16);
            float k3  = __builtin_bit_cast(float, uA.y & 0xffff0000u);
            float k4  = __builtin_bit_cast(float, uB.x << 16);
            float k5  = __builtin_bit_cast(float, uB.x & 0xffff0000u);
            float k6  = __builtin_bit_cast(float, uB.y << 16);
            float k7  = __builtin_bit_cast(float, uB.y & 0xffff0000u);
            float k8  = __builtin_bit_cast(float, uC.x << 16);
            float k9  = __builtin_bit_cast(float, uC.x & 0xffff0000u);
            float k10 = __builtin_bit_cast(float, uC.y << 16);
            float k11 = __builtin_bit_cast(float, uC.y & 0xffff0000u);
            int n = i * 9 + j * 3 + l;
            float dot0 = rpbase[n * 2 + 0] + q0*k0 + q1*k1 + q2*k2
                       + q3*k3 + q4*k4 + q5*k5;
            float dot1 = rpbase[n * 2 + 1] + q6*k6 + q7*k7 + q8*k8
                       + q9*k9 + q10*k10 + q11*k11;
            float e0 = __builtin_amdgcn_exp2f(dot0);
            float e1 = __builtin_amdgcn_exp2f(dot1);
            d0 += e0; d1 += e1;
            if (i == 0)      { ox0 -= e0; ox1 -= e1; }
            else if (i == 2) { ox0 += e0; ox1 += e1; }
            if (j == 0)      { oy0 -= e0; oy1 -= e1; }
            else if (j == 2) { oy0 += e0; oy1 += e1; }
            if (l == 0)      { oz0 -= e0; oz1 -= e1; }
            else if (l == 2) { oz0 += e0; oz1 += e1; }
        }
    }

    float inv0 = __builtin_amdgcn_rcpf(d0);
    float inv1 = __builtin_amdgcn_rcpf(d1);
    float* op = out + (size_t)(hp * 6) * NVOX + gvox;
    op[0*NVOX] = ox0 * inv0;
    op[1*NVOX] = oy0 * inv0;
    op[2*NVOX] = oz0 * inv0;
    op[3*NVOX] = ox1 * inv1;
    op[4*NVOX] = oy1 * inv1;
    op[5*NVOX] = oz1 * inv1;
}

extern "C" void kernel_launch(void* const* d_in, const int* in_sizes, int n_in,
                              void* d_out, int out_size, void* d_ws, size_t ws_size,
                              hipStream_t stream) {
    const float* q   = (const float*)d_in[0];
    const float* k   = (const float*)d_in[1];
    const float* rpb = (const float*)d_in[2];
    float* out = (float*)d_out;

    natt_kernel<<<1000, 256, 0, stream>>>(q, k, rpb, out);
}

// Round 7
// 18.882 us; speedup vs baseline: 1.9076x; 1.3123x over previous
//
#include <hip/hip_runtime.h>

// 3D neighborhood attention, 40^3, NH=8, HD=6, KS=3 (27 neighbors).
// Block = 4x4x4 voxel tile x 4 head-pairs (256 thr). 6x6x6 k-halo staged in
// LDS as packed f16 (v_cvt_pkrtz); zero-fill OOB -> score = rpb semantics.
// Inner loop: v_dot2_f32_f16 (fdot2), rpb as f32 accumulator init.
// LDS layout [hp][216 vox][6 dw], hp stride 1304 dw -> 4 dwords/bank exact.
// exp(s)=exp2(s*log2e): log2e folded into q-scale and rpb.

#define GS    40
#define NVOX  (GS*GS*GS)
#define HPW   1304          // per-head-pair LDS stride in dwords (216*6 + 8)

typedef __fp16 half2_t __attribute__((ext_vector_type(2)));

__device__ __forceinline__ float fdot2(half2_t a, half2_t b, float c) {
    return __builtin_amdgcn_fdot2(a, b, c, false);
}

__device__ __forceinline__ half2_t h2(unsigned int u) {
    return __builtin_bit_cast(half2_t, u);
}

__global__ __launch_bounds__(256) void natt_kernel(
    const float* __restrict__ q, const float* __restrict__ kk,
    const float* __restrict__ rpb, float* __restrict__ out)
{
    __shared__ unsigned int sk[4 * HPW];   // 20.9 KB
    __shared__ float srpb[4 * 27 * 2];

    int t = threadIdx.x;
    int b = blockIdx.x;
    int w = (b & 7) * 125 + (b >> 3);      // XCD chunking (bijective: 1000=8*125)
    int bz = w % 10, by = (w / 10) % 10, bx = w / 100;
    int x0 = bx * 4, y0 = by * 4, z0 = bz * 4;

    // ---- q f4 loads issued first (overlap with staging) ----
    int hp = t & 3;
    int v  = t >> 2;
    int vz = v & 3, vy = (v >> 2) & 3, vx = v >> 4;
    int gvox = (x0 + vx) * 1600 + (y0 + vy) * 40 + (z0 + vz);
    const float4* qp = (const float4*)q + (size_t)gvox * 12 + hp * 3;
    float4 qa = qp[0], qb = qp[1], qc = qp[2];

    if (t < 216) {
        int h = t / 27, n = t % 27;
        srpb[((h >> 1) * 27 + n) * 2 + (h & 1)] = rpb[t] * 1.4426950408889634f;
    }

    // ---- stage k halo as packed f16: 36 rows x 6 z x 12 f4 = 2592 f4 ----
    const float4* kk4 = (const float4*)kk;
    #pragma unroll
    for (int it = 0; it < 11; ++it) {
        int idx = t + it * 256;
        if (idx < 2592) {
            int row = idx / 72;            // xi*6+yi
            int off = idx - row * 72;
            int zz  = off / 12;            // z in halo row
            int g   = off - zz * 12;       // f4 within voxel
            int xi = row / 6, yi = row - xi * 6;
            int gx = x0 + xi - 1, gy = y0 + yi - 1, gz = z0 + zz - 1;
            float4 val = make_float4(0.f, 0.f, 0.f, 0.f);
            if (((unsigned)gx < GS) & ((unsigned)gy < GS) & ((unsigned)gz < GS))
                val = kk4[(gx * 1600 + gy * 40 + gz) * 12 + g];
            int hp_c = g / 3, cc = g - hp_c * 3;
            uint2 u;
            u.x = __builtin_bit_cast(unsigned int,
                    __builtin_amdgcn_cvt_pkrtz(val.x, val.y));
            u.y = __builtin_bit_cast(unsigned int,
                    __builtin_amdgcn_cvt_pkrtz(val.z, val.w));
            *(uint2*)(sk + hp_c * HPW + (row * 6 + zz) * 6 + cc * 2) = u;
        }
    }

    // ---- pack q into 6 half2, pre-scaled by 6^-0.5 * log2(e) ----
    const float QS = 0.4082482904638631f * 1.4426950408889634f;
    half2_t qh0 = __builtin_amdgcn_cvt_pkrtz(qa.x * QS, qa.y * QS);
    half2_t qh1 = __builtin_amdgcn_cvt_pkrtz(qa.z * QS, qa.w * QS);
    half2_t qh2 = __builtin_amdgcn_cvt_pkrtz(qb.x * QS, qb.y * QS);
    half2_t qh3 = __builtin_amdgcn_cvt_pkrtz(qb.z * QS, qb.w * QS);
    half2_t qh4 = __builtin_amdgcn_cvt_pkrtz(qc.x * QS, qc.y * QS);
    half2_t qh5 = __builtin_amdgcn_cvt_pkrtz(qc.z * QS, qc.w * QS);

    __syncthreads();

    float d0 = 0, d1 = 0;
    float ox0 = 0, ox1 = 0, oy0 = 0, oy1 = 0, oz0 = 0, oz1 = 0;

    const unsigned int* kb = sk + hp * HPW;
    const float* rpbase = srpb + hp * 54;

    #pragma unroll
    for (int i = 0; i < 3; ++i)
    #pragma unroll
    for (int j = 0; j < 3; ++j) {
        int hv0 = (vx + i) * 36 + (vy + j) * 6 + vz;
        #pragma unroll
        for (int l = 0; l < 3; ++l) {
            const uint2* p = (const uint2*)(kb + (hv0 + l) * 6);
            uint2 uA = p[0], uB = p[1], uC = p[2];
            int n = i * 9 + j * 3 + l;
            float dot0 = fdot2(qh0, h2(uA.x),
                         fdot2(qh1, h2(uA.y),
                         fdot2(qh2, h2(uB.x), rpbase[n * 2 + 0])));
            float dot1 = fdot2(qh3, h2(uB.y),
                         fdot2(qh4, h2(uC.x),
                         fdot2(qh5, h2(uC.y), rpbase[n * 2 + 1])));
            float e0 = __builtin_amdgcn_exp2f(dot0);
            float e1 = __builtin_amdgcn_exp2f(dot1);
            d0 += e0; d1 += e1;
            if (i == 0)      { ox0 -= e0; ox1 -= e1; }
            else if (i == 2) { ox0 += e0; ox1 += e1; }
            if (j == 0)      { oy0 -= e0; oy1 -= e1; }
            else if (j == 2) { oy0 += e0; oy1 += e1; }
            if (l == 0)      { oz0 -= e0; oz1 -= e1; }
            else if (l == 2) { oz0 += e0; oz1 += e1; }
        }
    }

    float inv0 = __builtin_amdgcn_rcpf(d0);
    float inv1 = __builtin_amdgcn_rcpf(d1);
    float* op = out + (size_t)(hp * 6) * NVOX + gvox;
    op[0*NVOX] = ox0 * inv0;
    op[1*NVOX] = oy0 * inv0;
    op[2*NVOX] = oz0 * inv0;
    op[3*NVOX] = ox1 * inv1;
    op[4*NVOX] = oy1 * inv1;
    op[5*NVOX] = oz1 * inv1;
}

extern "C" void kernel_launch(void* const* d_in, const int* in_sizes, int n_in,
                              void* d_out, int out_size, void* d_ws, size_t ws_size,
                              hipStream_t stream) {
    const float* q   = (const float*)d_in[0];
    const float* k   = (const float*)d_in[1];
    const float* rpb = (const float*)d_in[2];
    float* out = (float*)d_out;

    natt_kernel<<<1000, 256, 0, stream>>>(q, k, rpb, out);
}

// Round 8
// 15.179 us; speedup vs baseline: 2.3729x; 1.2439x over previous
//
#include <hip/hip_runtime.h>

// 3D neighborhood attention, 40^3, NH=8, HD=6, KS=3 (27 neighbors).
// Block = 4x4x4 voxel tile x 4 head-pairs (256 thr). 6x6x6 k-halo in LDS as
// packed f16, split into uint4-region (head0 dws + head1 dw0) and uint2-region
// -> exactly 1 ds_read_b128 + 1 ds_read_b64 per neighbor. rpb as float2 b64
// broadcast. Both heads accumulated as float2 (v_pk_add_f32). Structured
// reduction: per (i,j) sum over l first. exp2 with log2e folded into q & rpb.

#define GS    40
#define NVOX  (GS*GS*GS)
#define S4ST  872           // uint4-region hp stride in dwords (216*4+8,  ==8 mod 32)
#define S2ST  440           // uint2-region hp stride in dwords (216*2+8, ==24 mod 32)
#define S2OFF (4*S4ST)      // 3488 dw

typedef __fp16 half2_t __attribute__((ext_vector_type(2)));
typedef float  f2      __attribute__((ext_vector_type(2)));

__device__ __forceinline__ float fdot2(half2_t a, half2_t b, float c) {
    return __builtin_amdgcn_fdot2(a, b, c, false);
}
__device__ __forceinline__ half2_t h2(unsigned int u) {
    return __builtin_bit_cast(half2_t, u);
}

__global__ __launch_bounds__(256) void natt_kernel(
    const float* __restrict__ q, const float* __restrict__ kk,
    const float* __restrict__ rpb, float* __restrict__ out)
{
    __shared__ __align__(16) unsigned int sk[4 * S4ST + 4 * S2ST];  // 21 KB
    __shared__ float srpb[4 * 27 * 2];

    int t = threadIdx.x;
    int b = blockIdx.x;
    int w = (b & 7) * 125 + (b >> 3);      // XCD chunking (bijective: 1000=8*125)
    int bz = w % 10, by = (w / 10) % 10, bx = w / 100;
    int x0 = bx * 4, y0 = by * 4, z0 = bz * 4;

    // ---- q f4 loads issued first (overlap with staging) ----
    int hp = t & 3;
    int v  = t >> 2;
    int vz = v & 3, vy = (v >> 2) & 3, vx = v >> 4;
    int gvox = (x0 + vx) * 1600 + (y0 + vy) * 40 + (z0 + vz);
    const float4* qp = (const float4*)q + (size_t)gvox * 12 + hp * 3;
    float4 qa = qp[0], qb = qp[1], qc = qp[2];

    if (t < 216) {
        int h = t / 27, n = t % 27;
        srpb[((h >> 1) * 27 + n) * 2 + (h & 1)] = rpb[t] * 1.4426950408889634f;
    }

    // ---- stage k halo as packed f16: 36 rows x 6 z x 12 f4 = 2592 f4 ----
    const float4* kk4 = (const float4*)kk;
    #pragma unroll
    for (int it = 0; it < 11; ++it) {
        int idx = t + it * 256;
        if (idx < 2592) {
            int row = idx / 72;            // xi*6+yi
            int off = idx - row * 72;
            int zz  = off / 12;            // z in halo row
            int g   = off - zz * 12;       // f4 within voxel
            int xi = row / 6, yi = row - xi * 6;
            int gx = x0 + xi - 1, gy = y0 + yi - 1, gz = z0 + zz - 1;
            float4 val = make_float4(0.f, 0.f, 0.f, 0.f);
            if (((unsigned)gx < GS) & ((unsigned)gy < GS) & ((unsigned)gz < GS))
                val = kk4[(gx * 1600 + gy * 40 + gz) * 12 + g];
            int hp_c = g / 3, cc = g - hp_c * 3;
            int hvv  = row * 6 + zz;
            uint2 u;
            u.x = __builtin_bit_cast(unsigned int,
                    __builtin_amdgcn_cvt_pkrtz(val.x, val.y));
            u.y = __builtin_bit_cast(unsigned int,
                    __builtin_amdgcn_cvt_pkrtz(val.z, val.w));
            unsigned int* dst = (cc == 2)
                ? sk + S2OFF + hp_c * S2ST + hvv * 2
                : sk + hp_c * S4ST + hvv * 4 + cc * 2;
            *(uint2*)dst = u;
        }
    }

    // ---- pack q into 6 half2, pre-scaled by 6^-0.5 * log2(e) ----
    const float QS = 0.4082482904638631f * 1.4426950408889634f;
    half2_t qh0 = __builtin_amdgcn_cvt_pkrtz(qa.x * QS, qa.y * QS);
    half2_t qh1 = __builtin_amdgcn_cvt_pkrtz(qa.z * QS, qa.w * QS);
    half2_t qh2 = __builtin_amdgcn_cvt_pkrtz(qb.x * QS, qb.y * QS);
    half2_t qh3 = __builtin_amdgcn_cvt_pkrtz(qb.z * QS, qb.w * QS);
    half2_t qh4 = __builtin_amdgcn_cvt_pkrtz(qc.x * QS, qc.y * QS);
    half2_t qh5 = __builtin_amdgcn_cvt_pkrtz(qc.z * QS, qc.w * QS);

    __syncthreads();

    const uint4* k4p = (const uint4*)sk + hp * (S4ST / 4);
    const uint2* k2p = (const uint2*)(sk + S2OFF) + hp * (S2ST / 2);
    const f2*    rp2 = (const f2*)srpb + hp * 27;

    f2 den = {0, 0}, ozc = {0, 0};
    f2 xp = {0, 0}, xm = {0, 0}, yp = {0, 0}, ym = {0, 0};

    #pragma unroll
    for (int i = 0; i < 3; ++i)
    #pragma unroll
    for (int j = 0; j < 3; ++j) {
        int hv0 = (vx + i) * 36 + (vy + j) * 6 + vz;
        f2 ev[3];
        #pragma unroll
        for (int l = 0; l < 3; ++l) {
            uint4 a = k4p[hv0 + l];
            uint2 c = k2p[hv0 + l];
            f2 rp = rp2[i * 9 + j * 3 + l];
            float d0 = fdot2(qh0, h2(a.x),
                       fdot2(qh1, h2(a.y),
                       fdot2(qh2, h2(a.z), rp.x)));
            float d1 = fdot2(qh3, h2(a.w),
                       fdot2(qh4, h2(c.x),
                       fdot2(qh5, h2(c.y), rp.y)));
            f2 e;
            e.x = __builtin_amdgcn_exp2f(d0);
            e.y = __builtin_amdgcn_exp2f(d1);
            ev[l] = e;
        }
        f2 A = ev[0] + ev[1] + ev[2];     // 2 pk-adds
        den += A;
        ozc += ev[2] - ev[0];
        if (i == 0)      xm += A;
        else if (i == 2) xp += A;
        if (j == 0)      ym += A;
        else if (j == 2) yp += A;
    }

    f2 oxv = xp - xm, oyv = yp - ym;
    float inv0 = __builtin_amdgcn_rcpf(den.x);
    float inv1 = __builtin_amdgcn_rcpf(den.y);

    float* op = out + (size_t)(hp * 6) * NVOX + gvox;
    op[0*NVOX] = oxv.x * inv0;
    op[1*NVOX] = oyv.x * inv0;
    op[2*NVOX] = ozc.x * inv0;
    op[3*NVOX] = oxv.y * inv1;
    op[4*NVOX] = oyv.y * inv1;
    op[5*NVOX] = ozc.y * inv1;
}

extern "C" void kernel_launch(void* const* d_in, const int* in_sizes, int n_in,
                              void* d_out, int out_size, void* d_ws, size_t ws_size,
                              hipStream_t stream) {
    const float* q   = (const float*)d_in[0];
    const float* k   = (const float*)d_in[1];
    const float* rpb = (const float*)d_in[2];
    float* out = (float*)d_out;

    natt_kernel<<<1000, 256, 0, stream>>>(q, k, rpb, out);
}